// Round 2
// baseline (841.841 us; speedup 1.0000x reference)
//
#include <hip/hip_runtime.h>
#include <math.h>

#define TILE 64
#define KC 16

// ---------------- workspace layout (bytes) ----------------
// DD (64MB f64 dist) is aliased with PT/ymax/ymin/yf which are only live
// after topk has consumed DD within each layer iteration.
#define OFF_DD    0ull          // 8192*1024*8 = 67108864
#define OFF_PT    0ull          // alias: 8192*512*4 = 16777216
#define OFF_YMAX  16777216ull   // alias: 8388608
#define OFF_YMIN  25165824ull   // alias: 8388608
#define OFF_YF    0ull          // alias: 8192*1024*4 = 33554432 (final gemm out)
#define OFF_IDX   67108864ull   // 8*1024*20 int = 655360
#define OFF_H     67764224ull   // 8*1024*256 f32 = 8388608
#define OFF_FUSED 76152832ull   // 8*1024*512 f32 = 16777216
#define OFF_XX    92930048ull   // 8192 f64 = 65536
#define OFF_WCAT  92995584ull   // 512*128*4 = 262144
#define OFF_STATS 93257728ull   // 3072 doubles = 24576
#define OFF_COEF  93282304ull   // 3072 floats = 12288

// ---------------- fp32 tiled GEMM core: C(M,N) = A(M,K) * Bw(N,K)^T ----------------
__device__ __forceinline__ void gemm_tile_loop(
    const float* __restrict__ A, const float* __restrict__ Bw,
    int K, int lda, int ldb, int rowBase, int colBase,
    float acc[4][4], float* As, float* Bs)
{
  const int tid = threadIdx.x;
  const int tx = tid & 15, ty = tid >> 4;
  for (int k0 = 0; k0 < K; k0 += KC) {
    for (int l = 0; l < 4; ++l) {
      int flat = tid * 4 + l;           // 0..1023
      int kk = flat & (KC - 1);
      int row = flat >> 4;
      int gk = k0 + kk;
      float av = 0.f, bv = 0.f;
      if (gk < K) {
        av = A[(size_t)(rowBase + row) * lda + gk];
        bv = Bw[(size_t)(colBase + row) * ldb + gk];
      }
      As[kk * TILE + row] = av;
      Bs[kk * TILE + row] = bv;
    }
    __syncthreads();
#pragma unroll
    for (int kk = 0; kk < KC; ++kk) {
      float a0[4], b0[4];
#pragma unroll
      for (int i = 0; i < 4; ++i) a0[i] = As[kk * TILE + ty * 4 + i];
#pragma unroll
      for (int j = 0; j < 4; ++j) b0[j] = Bs[kk * TILE + tx * 4 + j];
#pragma unroll
      for (int i = 0; i < 4; ++i)
#pragma unroll
        for (int j = 0; j < 4; ++j)
          acc[i][j] = fmaf(a0[i], b0[j], acc[i][j]);
    }
    __syncthreads();
  }
}

// ---------------- K0: squared norms per point (f64) ----------------
__global__ __launch_bounds__(256) void xx_kernel(const float* __restrict__ H, int C,
                                                 double* __restrict__ xx) {
  int m = blockIdx.x * 256 + threadIdx.x;
  if (m < 8192) {
    double s = 0.0;
    for (int c = 0; c < C; ++c) { double h = (double)H[(size_t)m * C + c]; s = fma(h, h, s); }
    xx[m] = s;
  }
}

// ---------------- K1: neg squared distance matrix per batch (f64 accumulate) ----------------
__global__ __launch_bounds__(256) void dist_kernel(const float* __restrict__ H, int C,
                                                   const double* __restrict__ xx,
                                                   double* __restrict__ D) {
  __shared__ double As[KC * TILE], Bs[KC * TILE];
  int bz = blockIdx.z;
  int rowBase = bz * 1024 + blockIdx.y * 64;
  int colBase = bz * 1024 + blockIdx.x * 64;
  const int tid = threadIdx.x;
  const int tx = tid & 15, ty = tid >> 4;
  double acc[4][4] = {};
  for (int k0 = 0; k0 < C; k0 += KC) {
    for (int l = 0; l < 4; ++l) {
      int flat = tid * 4 + l;
      int kk = flat & (KC - 1);
      int row = flat >> 4;
      int gk = k0 + kk;
      double av = 0.0, bv = 0.0;
      if (gk < C) {
        av = (double)H[(size_t)(rowBase + row) * C + gk];
        bv = (double)H[(size_t)(colBase + row) * C + gk];
      }
      As[kk * TILE + row] = av;
      Bs[kk * TILE + row] = bv;
    }
    __syncthreads();
#pragma unroll
    for (int kk = 0; kk < KC; ++kk) {
      double a0[4], b0[4];
#pragma unroll
      for (int i = 0; i < 4; ++i) a0[i] = As[kk * TILE + ty * 4 + i];
#pragma unroll
      for (int j = 0; j < 4; ++j) b0[j] = Bs[kk * TILE + tx * 4 + j];
#pragma unroll
      for (int i = 0; i < 4; ++i)
#pragma unroll
        for (int j = 0; j < 4; ++j)
          acc[i][j] = fma(a0[i], b0[j], acc[i][j]);
    }
    __syncthreads();
  }
#pragma unroll
  for (int i = 0; i < 4; ++i) {
    int gi = blockIdx.y * 64 + ty * 4 + i;
    double xi = xx[rowBase + ty * 4 + i];
#pragma unroll
    for (int j = 0; j < 4; ++j) {
      int gj = blockIdx.x * 64 + tx * 4 + j;
      double v = 2.0 * acc[i][j] - xi - xx[colBase + tx * 4 + j];
      D[((size_t)bz << 20) + (size_t)gi * 1024 + gj] = v;
    }
  }
}

// ---------------- K2: top-20 per row (ties -> smaller index, as lax.top_k) ----------------
__global__ __launch_bounds__(256) void topk_kernel(const double* __restrict__ D,
                                                   int* __restrict__ idx) {
  int lane = threadIdx.x & 63;
  int row = blockIdx.x * 4 + (threadIdx.x >> 6);   // 8192 rows
  const double* drow = D + (size_t)row * 1024;
  double v[16];
#pragma unroll
  for (int t = 0; t < 16; ++t) v[t] = drow[lane + 64 * t];
  for (int j = 0; j < 20; ++j) {
    double bv = v[0]; int bt = 0;
#pragma unroll
    for (int t = 1; t < 16; ++t) if (v[t] > bv) { bv = v[t]; bt = t; }
    int bcol = lane + 64 * bt;
#pragma unroll
    for (int off = 1; off < 64; off <<= 1) {
      double ov = __shfl_xor(bv, off, 64);
      int    oc = __shfl_xor(bcol, off, 64);
      if (ov > bv || (ov == bv && oc < bcol)) { bv = ov; bcol = oc; }
    }
    if (lane == (bcol & 63)) v[bcol >> 6] = -INFINITY;
    if (lane == 0) idx[row * 20 + j] = bcol;
  }
}

// ---------------- K3a: Wcat = [W1 ; W2-W1]  (W is (out, 2C) row-major) ----------------
__global__ __launch_bounds__(256) void wcat_kernel(const float* __restrict__ W,
                                                   float* __restrict__ Wcat, int outc, int C) {
  int i = blockIdx.x * 256 + threadIdx.x;
  if (i < outc * C) {
    int o = i / C, c = i % C;
    float w1 = W[(size_t)o * 2 * C + c];
    float w2 = W[(size_t)o * 2 * C + C + c];
    Wcat[(size_t)o * C + c] = w1;
    Wcat[(size_t)(outc + o) * C + c] = w2 - w1;
  }
}

// ---------------- K3b: PT(M, 2*out) = H(M,C) @ Wcat^T ----------------
__global__ __launch_bounds__(256) void pt_gemm(const float* __restrict__ A,
                                               const float* __restrict__ Bw,
                                               float* __restrict__ Out, int K, int Nn) {
  __shared__ float As[KC * TILE], Bs[KC * TILE];
  int rowBase = blockIdx.y * 64, colBase = blockIdx.x * 64;
  float acc[4][4] = {};
  gemm_tile_loop(A, Bw, K, K, K, rowBase, colBase, acc, As, Bs);
  int tx = threadIdx.x & 15, ty = threadIdx.x >> 4;
#pragma unroll
  for (int i = 0; i < 4; ++i)
#pragma unroll
    for (int j = 0; j < 4; ++j)
      Out[(size_t)(rowBase + ty * 4 + i) * Nn + colBase + tx * 4 + j] = acc[i][j];
}

// ---------------- K4: gather + max/min over k + channel stats ----------------
__global__ __launch_bounds__(256) void edge_reduce(const float* __restrict__ PT,
                                                   const int* __restrict__ idx,
                                                   float* __restrict__ ymax, float* __restrict__ ymin,
                                                   double* __restrict__ sum, double* __restrict__ sumsq,
                                                   int outc, int l2) {
  __shared__ int sidx[16 * 20];
  __shared__ float ssum[256], ssq[256];
  int tid = threadIdx.x;
  int base = blockIdx.x * 16;
  for (int i = tid; i < 320; i += 256) sidx[i] = idx[base * 20 + i];
  __syncthreads();
  int o = tid & (outc - 1);
  int rs = tid >> l2;
  int R = 256 >> l2;
  int twoc = 2 * outc;
  float ls = 0.f, lq = 0.f;
  for (int r = rs; r < 16; r += R) {
    int m = base + r;
    int boff = (m >> 10) << 10;
    float tv = PT[(size_t)m * twoc + outc + o];
    float vmax = -INFINITY, vmin = INFINITY;
#pragma unroll
    for (int k = 0; k < 20; ++k) {
      int nb = sidx[r * 20 + k];
      float p = PT[(size_t)(boff + nb) * twoc + o];
      float y = p + tv;
      vmax = fmaxf(vmax, y);
      vmin = fminf(vmin, y);
      ls += y;
      lq = fmaf(y, y, lq);
    }
    ymax[(size_t)m * outc + o] = vmax;
    ymin[(size_t)m * outc + o] = vmin;
  }
  ssum[tid] = ls; ssq[tid] = lq;
  __syncthreads();
  if (tid < outc) {
    float s = ssum[tid], q = ssq[tid];
    for (int rr = 1; rr < R; ++rr) { s += ssum[tid + rr * outc]; q += ssq[tid + rr * outc]; }
    atomicAdd(&sum[tid], (double)s);
    atomicAdd(&sumsq[tid], (double)q);
  }
}

// ---------------- K5: per-channel affine coefficients from stats (f64) ----------------
__global__ __launch_bounds__(256) void coef_kernel(const double* __restrict__ sum,
                                                   const double* __restrict__ sumsq,
                                                   const float* __restrict__ g,
                                                   const float* __restrict__ b,
                                                   float* __restrict__ cA, float* __restrict__ cC,
                                                   int outc, double count) {
  int o = blockIdx.x * 256 + threadIdx.x;
  if (o < outc) {
    double mean = sum[o] / count;
    double var = sumsq[o] / count - mean * mean;
    double a = (double)g[o] / sqrt(var + 1e-5);
    cA[o] = (float)a;
    cC[o] = (float)((double)b[o] - mean * a);
  }
}

// ---------------- K6: pick max/min per sign(a), affine + LeakyReLU, scatter to H & fused ----------------
__global__ __launch_bounds__(256) void edge_epi(const float* __restrict__ ymax,
                                                const float* __restrict__ ymin,
                                                const float* __restrict__ cA, const float* __restrict__ cC,
                                                float* __restrict__ Hout, float* __restrict__ fused,
                                                int outc, int l2, int choff) {
  int i = blockIdx.x * 256 + threadIdx.x;    // over 8192*outc
  int m = i >> l2;
  int o = i & (outc - 1);
  float a = cA[o], c = cC[o];
  float v = (a >= 0.f) ? ymax[i] : ymin[i];
  float y = fmaf(a, v, c);
  y = (y > 0.f) ? y : 0.2f * y;
  Hout[i] = y;
  fused[(size_t)m * 512 + choff + o] = y;
}

// ---------------- K7: final GEMM yf(8192,1024) = fused(8192,512) @ Wf^T + stats ----------------
__global__ __launch_bounds__(256) void final_gemm(const float* __restrict__ A,
                                                  const float* __restrict__ Bw,
                                                  float* __restrict__ Out,
                                                  double* __restrict__ sum, double* __restrict__ sumsq) {
  __shared__ float As[KC * TILE], Bs[KC * TILE];
  int rowBase = blockIdx.y * 64, colBase = blockIdx.x * 64;
  float acc[4][4] = {};
  gemm_tile_loop(A, Bw, 512, 512, 512, rowBase, colBase, acc, As, Bs);
  int tid = threadIdx.x, tx = tid & 15, ty = tid >> 4;
  float s[4] = {0, 0, 0, 0}, q[4] = {0, 0, 0, 0};
#pragma unroll
  for (int i = 0; i < 4; ++i)
#pragma unroll
    for (int j = 0; j < 4; ++j) {
      float v = acc[i][j];
      Out[(size_t)(rowBase + ty * 4 + i) * 1024 + colBase + tx * 4 + j] = v;
      s[j] += v;
      q[j] = fmaf(v, v, q[j]);
    }
  __syncthreads();
#pragma unroll
  for (int j = 0; j < 4; ++j) { As[ty * 64 + tx * 4 + j] = s[j]; Bs[ty * 64 + tx * 4 + j] = q[j]; }
  __syncthreads();
  if (tid < 64) {
    float ss = 0.f, qq = 0.f;
    for (int r = 0; r < 16; ++r) { ss += As[r * 64 + tid]; qq += Bs[r * 64 + tid]; }
    atomicAdd(&sum[colBase + tid], (double)ss);
    atomicAdd(&sumsq[colBase + tid], (double)qq);
  }
}

// ---------------- K8: final normalize + LeakyReLU ----------------
__global__ __launch_bounds__(256) void final_epi(const float* __restrict__ yf,
                                                 const float* __restrict__ cA, const float* __restrict__ cC,
                                                 float* __restrict__ out) {
  int i = blockIdx.x * 256 + threadIdx.x;     // over 8192*1024
  int o = i & 1023;
  float y = fmaf(cA[o], yf[i], cC[o]);
  out[i] = (y > 0.f) ? y : 0.2f * y;
}

extern "C" void kernel_launch(void* const* d_in, const int* in_sizes, int n_in,
                              void* d_out, int out_size, void* d_ws, size_t ws_size,
                              hipStream_t stream) {
  const float* x = (const float*)d_in[0];
  const float* W[4]  = {(const float*)d_in[1], (const float*)d_in[4], (const float*)d_in[7], (const float*)d_in[10]};
  const float* g[4]  = {(const float*)d_in[2], (const float*)d_in[5], (const float*)d_in[8], (const float*)d_in[11]};
  const float* bb[4] = {(const float*)d_in[3], (const float*)d_in[6], (const float*)d_in[9], (const float*)d_in[12]};
  const float* Wf  = (const float*)d_in[13];
  const float* gf  = (const float*)d_in[14];
  const float* bfp = (const float*)d_in[15];
  float* out = (float*)d_out;

  char* ws = (char*)d_ws;
  double* DD    = (double*)(ws + OFF_DD);
  float*  PT    = (float*)(ws + OFF_PT);
  float*  ymax  = (float*)(ws + OFF_YMAX);
  float*  ymin  = (float*)(ws + OFF_YMIN);
  float*  yf    = (float*)(ws + OFF_YF);
  int*    idxb  = (int*)(ws + OFF_IDX);
  float*  Hbuf  = (float*)(ws + OFF_H);
  float*  fused = (float*)(ws + OFF_FUSED);
  double* xxb   = (double*)(ws + OFF_XX);
  float*  wcat  = (float*)(ws + OFF_WCAT);
  double* stats = (double*)(ws + OFF_STATS);
  float*  coefb = (float*)(ws + OFF_COEF);

  hipMemsetAsync(stats, 0, 24576, stream);   // zero all stat accumulators (ws is poisoned)

  const int Cin[4]   = {3, 64, 64, 128};
  const int Cout[4]  = {64, 64, 128, 256};
  const int choff[4] = {0, 64, 128, 256};
  const float* Hin = x;
  size_t soff = 0, coff = 0;

  for (int i = 0; i < 4; ++i) {
    int C = Cin[i], oc = Cout[i];
    int l2 = (oc == 64) ? 6 : (oc == 128) ? 7 : 8;
    double* sum = stats + soff;  double* sumsq = sum + oc;  soff += 2 * (size_t)oc;
    float* cA = coefb + coff;    float* cC = cA + oc;       coff += 2 * (size_t)oc;

    xx_kernel<<<32, 256, 0, stream>>>(Hin, C, xxb);
    dist_kernel<<<dim3(16, 16, 8), 256, 0, stream>>>(Hin, C, xxb, DD);
    topk_kernel<<<2048, 256, 0, stream>>>(DD, idxb);
    wcat_kernel<<<(oc * C + 255) / 256, 256, 0, stream>>>(W[i], wcat, oc, C);
    pt_gemm<<<dim3(2 * oc / 64, 128), 256, 0, stream>>>(Hin, wcat, PT, C, 2 * oc);
    edge_reduce<<<512, 256, 0, stream>>>(PT, idxb, ymax, ymin, sum, sumsq, oc, l2);
    coef_kernel<<<1, 256, 0, stream>>>(sum, sumsq, g[i], bb[i], cA, cC, oc, 163840.0);
    edge_epi<<<(8192 * oc) / 256, 256, 0, stream>>>(ymax, ymin, cA, cC, Hbuf, fused, oc, l2, choff[i]);
    Hin = Hbuf;
  }

  double* sumF = stats + soff;  double* sumsqF = sumF + 1024;
  float* cAF = coefb + coff;    float* cCF = cAF + 1024;
  final_gemm<<<dim3(16, 128), 256, 0, stream>>>(fused, Wf, yf, sumF, sumsqF);
  coef_kernel<<<4, 256, 0, stream>>>(sumF, sumsqF, gf, bfp, cAF, cCF, 1024, 8192.0);
  final_epi<<<8192 * 1024 / 256, 256, 0, stream>>>(yf, cAF, cCF, out);
}

// Round 3
// 755.428 us; speedup vs baseline: 1.1144x; 1.1144x over previous
//
#include <hip/hip_runtime.h>
#include <math.h>

#define TILE 64
#define KC 16

typedef __attribute__((ext_vector_type(8))) short short8;
typedef __attribute__((ext_vector_type(4))) float float4v;
typedef const __attribute__((address_space(1))) void* gptr_t;
typedef __attribute__((address_space(3))) void* lptr_t;

// ---------------- workspace layout (bytes) ----------------
// DD (64MB f64 dist) aliased with PT/ymax/ymin (layer loop) and YF (final).
#define OFF_DD    0ull          // 8192*1024*8 = 67108864
#define OFF_PT    0ull          // alias: 8192*512*4 = 16777216
#define OFF_YMAX  16777216ull   // alias: 8388608
#define OFF_YMIN  25165824ull   // alias: 8388608
#define OFF_YF    0ull          // alias: 8192*1024*4 = 33554432 (final gemm out)
#define OFF_IDX   67108864ull   // 655360
#define OFF_H     67764224ull   // 8388608
#define OFF_FUSB  76152832ull   // 8192*512*2 = 8388608 (bf16 fused)
#define OFF_WFB   84541440ull   // 1024*512*2 = 1048576 (bf16 Wf)
#define OFF_XX    85590016ull   // 65536
#define OFF_WCAT  85655552ull   // 262144
#define OFF_STATS 85917696ull   // 24576
#define OFF_COEF  85942272ull   // 12288

__device__ __forceinline__ unsigned short f2bf(float f) {
  unsigned int u = __float_as_uint(f);
  unsigned int r = (u + 0x7fffu + ((u >> 16) & 1u)) >> 16;
  return (unsigned short)r;
}

// ---------------- fp32 tiled GEMM core: C(M,N) = A(M,K) * Bw(N,K)^T ----------------
__device__ __forceinline__ void gemm_tile_loop(
    const float* __restrict__ A, const float* __restrict__ Bw,
    int K, int lda, int ldb, int rowBase, int colBase,
    float acc[4][4], float* As, float* Bs)
{
  const int tid = threadIdx.x;
  const int tx = tid & 15, ty = tid >> 4;
  for (int k0 = 0; k0 < K; k0 += KC) {
    for (int l = 0; l < 4; ++l) {
      int flat = tid * 4 + l;           // 0..1023
      int kk = flat & (KC - 1);
      int row = flat >> 4;
      int gk = k0 + kk;
      float av = 0.f, bv = 0.f;
      if (gk < K) {
        av = A[(size_t)(rowBase + row) * lda + gk];
        bv = Bw[(size_t)(colBase + row) * ldb + gk];
      }
      As[kk * TILE + row] = av;
      Bs[kk * TILE + row] = bv;
    }
    __syncthreads();
#pragma unroll
    for (int kk = 0; kk < KC; ++kk) {
      float a0[4], b0[4];
#pragma unroll
      for (int i = 0; i < 4; ++i) a0[i] = As[kk * TILE + ty * 4 + i];
#pragma unroll
      for (int j = 0; j < 4; ++j) b0[j] = Bs[kk * TILE + tx * 4 + j];
#pragma unroll
      for (int i = 0; i < 4; ++i)
#pragma unroll
        for (int j = 0; j < 4; ++j)
          acc[i][j] = fmaf(a0[i], b0[j], acc[i][j]);
    }
    __syncthreads();
  }
}

// ---------------- K0: squared norms per point (f64) ----------------
__global__ __launch_bounds__(256) void xx_kernel(const float* __restrict__ H, int C,
                                                 double* __restrict__ xx) {
  int m = blockIdx.x * 256 + threadIdx.x;
  if (m < 8192) {
    double s = 0.0;
    for (int c = 0; c < C; ++c) { double h = (double)H[(size_t)m * C + c]; s = fma(h, h, s); }
    xx[m] = s;
  }
}

// ---------------- K1: neg squared distance matrix per batch (f64 accumulate) ----------------
__global__ __launch_bounds__(256) void dist_kernel(const float* __restrict__ H, int C,
                                                   const double* __restrict__ xx,
                                                   double* __restrict__ D) {
  __shared__ double As[KC * TILE], Bs[KC * TILE];
  int bz = blockIdx.z;
  int rowBase = bz * 1024 + blockIdx.y * 64;
  int colBase = bz * 1024 + blockIdx.x * 64;
  const int tid = threadIdx.x;
  const int tx = tid & 15, ty = tid >> 4;
  double acc[4][4] = {};
  for (int k0 = 0; k0 < C; k0 += KC) {
    for (int l = 0; l < 4; ++l) {
      int flat = tid * 4 + l;
      int kk = flat & (KC - 1);
      int row = flat >> 4;
      int gk = k0 + kk;
      double av = 0.0, bv = 0.0;
      if (gk < C) {
        av = (double)H[(size_t)(rowBase + row) * C + gk];
        bv = (double)H[(size_t)(colBase + row) * C + gk];
      }
      As[kk * TILE + row] = av;
      Bs[kk * TILE + row] = bv;
    }
    __syncthreads();
#pragma unroll
    for (int kk = 0; kk < KC; ++kk) {
      double a0[4], b0[4];
#pragma unroll
      for (int i = 0; i < 4; ++i) a0[i] = As[kk * TILE + ty * 4 + i];
#pragma unroll
      for (int j = 0; j < 4; ++j) b0[j] = Bs[kk * TILE + tx * 4 + j];
#pragma unroll
      for (int i = 0; i < 4; ++i)
#pragma unroll
        for (int j = 0; j < 4; ++j)
          acc[i][j] = fma(a0[i], b0[j], acc[i][j]);
    }
    __syncthreads();
  }
#pragma unroll
  for (int i = 0; i < 4; ++i) {
    int gi = blockIdx.y * 64 + ty * 4 + i;
    double xi = xx[rowBase + ty * 4 + i];
#pragma unroll
    for (int j = 0; j < 4; ++j) {
      int gj = blockIdx.x * 64 + tx * 4 + j;
      double v = 2.0 * acc[i][j] - xi - xx[colBase + tx * 4 + j];
      D[((size_t)bz << 20) + (size_t)gi * 1024 + gj] = v;
    }
  }
}

// ---------------- K2: top-20 per row (ties -> smaller index, as lax.top_k) ----------------
__global__ __launch_bounds__(256) void topk_kernel(const double* __restrict__ D,
                                                   int* __restrict__ idx) {
  int lane = threadIdx.x & 63;
  int row = blockIdx.x * 4 + (threadIdx.x >> 6);   // 8192 rows
  const double* drow = D + (size_t)row * 1024;
  double v[16];
#pragma unroll
  for (int t = 0; t < 16; ++t) v[t] = drow[lane + 64 * t];
  for (int j = 0; j < 20; ++j) {
    double bv = v[0]; int bt = 0;
#pragma unroll
    for (int t = 1; t < 16; ++t) if (v[t] > bv) { bv = v[t]; bt = t; }
    int bcol = lane + 64 * bt;
#pragma unroll
    for (int off = 1; off < 64; off <<= 1) {
      double ov = __shfl_xor(bv, off, 64);
      int    oc = __shfl_xor(bcol, off, 64);
      if (ov > bv || (ov == bv && oc < bcol)) { bv = ov; bcol = oc; }
    }
    if (lane == (bcol & 63)) v[bcol >> 6] = -INFINITY;
    if (lane == 0) idx[row * 20 + j] = bcol;
  }
}

// ---------------- K3a: Wcat = [W1 ; W2-W1]  (W is (out, 2C) row-major) ----------------
__global__ __launch_bounds__(256) void wcat_kernel(const float* __restrict__ W,
                                                   float* __restrict__ Wcat, int outc, int C) {
  int i = blockIdx.x * 256 + threadIdx.x;
  if (i < outc * C) {
    int o = i / C, c = i % C;
    float w1 = W[(size_t)o * 2 * C + c];
    float w2 = W[(size_t)o * 2 * C + C + c];
    Wcat[(size_t)o * C + c] = w1;
    Wcat[(size_t)(outc + o) * C + c] = w2 - w1;
  }
}

// ---------------- K3b: PT(M, 2*out) = H(M,C) @ Wcat^T ----------------
__global__ __launch_bounds__(256) void pt_gemm(const float* __restrict__ A,
                                               const float* __restrict__ Bw,
                                               float* __restrict__ Out, int K, int Nn) {
  __shared__ float As[KC * TILE], Bs[KC * TILE];
  int rowBase = blockIdx.y * 64, colBase = blockIdx.x * 64;
  float acc[4][4] = {};
  gemm_tile_loop(A, Bw, K, K, K, rowBase, colBase, acc, As, Bs);
  int tx = threadIdx.x & 15, ty = threadIdx.x >> 4;
#pragma unroll
  for (int i = 0; i < 4; ++i)
#pragma unroll
    for (int j = 0; j < 4; ++j)
      Out[(size_t)(rowBase + ty * 4 + i) * Nn + colBase + tx * 4 + j] = acc[i][j];
}

// ---------------- K4: gather + max/min over k + channel stats ----------------
__global__ __launch_bounds__(256) void edge_reduce(const float* __restrict__ PT,
                                                   const int* __restrict__ idx,
                                                   float* __restrict__ ymax, float* __restrict__ ymin,
                                                   double* __restrict__ sum, double* __restrict__ sumsq,
                                                   int outc, int l2) {
  __shared__ int sidx[16 * 20];
  __shared__ float ssum[256], ssq[256];
  int tid = threadIdx.x;
  int base = blockIdx.x * 16;
  for (int i = tid; i < 320; i += 256) sidx[i] = idx[base * 20 + i];
  __syncthreads();
  int o = tid & (outc - 1);
  int rs = tid >> l2;
  int R = 256 >> l2;
  int twoc = 2 * outc;
  float ls = 0.f, lq = 0.f;
  for (int r = rs; r < 16; r += R) {
    int m = base + r;
    int boff = (m >> 10) << 10;
    float tv = PT[(size_t)m * twoc + outc + o];
    float vmax = -INFINITY, vmin = INFINITY;
#pragma unroll
    for (int k = 0; k < 20; ++k) {
      int nb = sidx[r * 20 + k];
      float p = PT[(size_t)(boff + nb) * twoc + o];
      float y = p + tv;
      vmax = fmaxf(vmax, y);
      vmin = fminf(vmin, y);
      ls += y;
      lq = fmaf(y, y, lq);
    }
    ymax[(size_t)m * outc + o] = vmax;
    ymin[(size_t)m * outc + o] = vmin;
  }
  ssum[tid] = ls; ssq[tid] = lq;
  __syncthreads();
  if (tid < outc) {
    float s = ssum[tid], q = ssq[tid];
    for (int rr = 1; rr < R; ++rr) { s += ssum[tid + rr * outc]; q += ssq[tid + rr * outc]; }
    atomicAdd(&sum[tid], (double)s);
    atomicAdd(&sumsq[tid], (double)q);
  }
}

// ---------------- K5: per-channel affine coefficients from stats (f64) ----------------
__global__ __launch_bounds__(256) void coef_kernel(const double* __restrict__ sum,
                                                   const double* __restrict__ sumsq,
                                                   const float* __restrict__ g,
                                                   const float* __restrict__ b,
                                                   float* __restrict__ cA, float* __restrict__ cC,
                                                   int outc, double count) {
  int o = blockIdx.x * 256 + threadIdx.x;
  if (o < outc) {
    double mean = sum[o] / count;
    double var = sumsq[o] / count - mean * mean;
    double a = (double)g[o] / sqrt(var + 1e-5);
    cA[o] = (float)a;
    cC[o] = (float)((double)b[o] - mean * a);
  }
}

// ---------------- K6: pick max/min per sign(a), affine + LeakyReLU, scatter to H & fused(bf16) ----------------
__global__ __launch_bounds__(256) void edge_epi(const float* __restrict__ ymax,
                                                const float* __restrict__ ymin,
                                                const float* __restrict__ cA, const float* __restrict__ cC,
                                                float* __restrict__ Hout, unsigned short* __restrict__ fusedb,
                                                int outc, int l2, int choff) {
  int i = blockIdx.x * 256 + threadIdx.x;    // over 8192*outc
  int m = i >> l2;
  int o = i & (outc - 1);
  float a = cA[o], c = cC[o];
  float v = (a >= 0.f) ? ymax[i] : ymin[i];
  float y = fmaf(a, v, c);
  y = (y > 0.f) ? y : 0.2f * y;
  Hout[i] = y;
  fusedb[(size_t)m * 512 + choff + o] = f2bf(y);
}

// ---------------- K6b: fp32 -> bf16 elementwise ----------------
__global__ __launch_bounds__(256) void cvt_bf16(const float* __restrict__ in,
                                                unsigned short* __restrict__ out, int n) {
  int i = blockIdx.x * 256 + threadIdx.x;
  if (i < n) out[i] = f2bf(in[i]);
}

// ---------------- K7: final GEMM (MFMA bf16): yf(8192,1024) = fusedb @ Wfb^T ----------------
__global__ __launch_bounds__(256) void final_gemm_mfma(const unsigned short* __restrict__ A,
                                                       const unsigned short* __restrict__ B,
                                                       float* __restrict__ C) {
  __shared__ unsigned short As[128 * 32];
  __shared__ unsigned short Bs[128 * 32];
  const int tid = threadIdx.x;
  const int lane = tid & 63;
  const int w = tid >> 6;             // wave 0..3
  const int wm = w >> 1, wn = w & 1;  // 2x2 wave grid, each wave 64x64
  const int rowBase = blockIdx.y * 128;
  const int colBase = blockIdx.x * 128;
  const int quad = lane >> 4;
  const int l15 = lane & 15;

  float4v acc[4][4] = {};

  for (int k0 = 0; k0 < 512; k0 += 32) {
#pragma unroll
    for (int q = 0; q < 2; ++q) {
      int ch = (w * 2 + q) * 64 + lane;          // 0..511, 16B chunks
      int r = ch >> 2, cp = ch & 3;
      const unsigned short* ga = A + (size_t)(rowBase + r) * 512 + k0 + cp * 8;
      const unsigned short* gb = B + (size_t)(colBase + r) * 512 + k0 + cp * 8;
      __builtin_amdgcn_global_load_lds((gptr_t)ga, (lptr_t)(As + (size_t)(w * 2 + q) * 512), 16, 0, 0);
      __builtin_amdgcn_global_load_lds((gptr_t)gb, (lptr_t)(Bs + (size_t)(w * 2 + q) * 512), 16, 0, 0);
    }
    __syncthreads();
    short8 af[4], bf[4];
#pragma unroll
    for (int mi = 0; mi < 4; ++mi)
      af[mi] = *(const short8*)(As + (wm * 64 + mi * 16 + l15) * 32 + quad * 8);
#pragma unroll
    for (int ni = 0; ni < 4; ++ni)
      bf[ni] = *(const short8*)(Bs + (wn * 64 + ni * 16 + l15) * 32 + quad * 8);
#pragma unroll
    for (int mi = 0; mi < 4; ++mi)
#pragma unroll
      for (int ni = 0; ni < 4; ++ni)
        acc[mi][ni] = __builtin_amdgcn_mfma_f32_16x16x32_bf16(af[mi], bf[ni], acc[mi][ni], 0, 0, 0);
    __syncthreads();
  }
#pragma unroll
  for (int mi = 0; mi < 4; ++mi)
#pragma unroll
    for (int ni = 0; ni < 4; ++ni)
#pragma unroll
      for (int r = 0; r < 4; ++r) {
        int gm = rowBase + wm * 64 + mi * 16 + quad * 4 + r;
        int gn = colBase + wn * 64 + ni * 16 + l15;
        C[(size_t)gm * 1024 + gn] = acc[mi][ni][r];
      }
}

// ---------------- K7b: per-column sums of yf (for final BN stats) ----------------
__global__ __launch_bounds__(256) void col_stats(const float* __restrict__ yf,
                                                 double* __restrict__ sum, double* __restrict__ sumsq) {
  int col = blockIdx.x * 256 + threadIdx.x;   // 0..1023
  int r0 = blockIdx.y * 128;
  float s = 0.f, q = 0.f;
  for (int r = 0; r < 128; ++r) {
    float v = yf[(size_t)(r0 + r) * 1024 + col];
    s += v;
    q = fmaf(v, v, q);
  }
  atomicAdd(&sum[col], (double)s);
  atomicAdd(&sumsq[col], (double)q);
}

// ---------------- K8: final normalize + LeakyReLU ----------------
__global__ __launch_bounds__(256) void final_epi(const float* __restrict__ yf,
                                                 const float* __restrict__ cA, const float* __restrict__ cC,
                                                 float* __restrict__ out) {
  int i = blockIdx.x * 256 + threadIdx.x;     // over 8192*1024
  int o = i & 1023;
  float y = fmaf(cA[o], yf[i], cC[o]);
  out[i] = (y > 0.f) ? y : 0.2f * y;
}

extern "C" void kernel_launch(void* const* d_in, const int* in_sizes, int n_in,
                              void* d_out, int out_size, void* d_ws, size_t ws_size,
                              hipStream_t stream) {
  const float* x = (const float*)d_in[0];
  const float* W[4]  = {(const float*)d_in[1], (const float*)d_in[4], (const float*)d_in[7], (const float*)d_in[10]};
  const float* g[4]  = {(const float*)d_in[2], (const float*)d_in[5], (const float*)d_in[8], (const float*)d_in[11]};
  const float* bb[4] = {(const float*)d_in[3], (const float*)d_in[6], (const float*)d_in[9], (const float*)d_in[12]};
  const float* Wf  = (const float*)d_in[13];
  const float* gf  = (const float*)d_in[14];
  const float* bfp = (const float*)d_in[15];
  float* out = (float*)d_out;

  char* ws = (char*)d_ws;
  double* DD    = (double*)(ws + OFF_DD);
  float*  PT    = (float*)(ws + OFF_PT);
  float*  ymax  = (float*)(ws + OFF_YMAX);
  float*  ymin  = (float*)(ws + OFF_YMIN);
  float*  yf    = (float*)(ws + OFF_YF);
  int*    idxb  = (int*)(ws + OFF_IDX);
  float*  Hbuf  = (float*)(ws + OFF_H);
  unsigned short* fusedb = (unsigned short*)(ws + OFF_FUSB);
  unsigned short* wfb    = (unsigned short*)(ws + OFF_WFB);
  double* xxb   = (double*)(ws + OFF_XX);
  float*  wcat  = (float*)(ws + OFF_WCAT);
  double* stats = (double*)(ws + OFF_STATS);
  float*  coefb = (float*)(ws + OFF_COEF);

  hipMemsetAsync(stats, 0, 24576, stream);   // zero all stat accumulators (ws is poisoned)
  cvt_bf16<<<(524288 + 255) / 256, 256, 0, stream>>>(Wf, wfb, 524288);

  const int Cin[4]   = {3, 64, 64, 128};
  const int Cout[4]  = {64, 64, 128, 256};
  const int choff[4] = {0, 64, 128, 256};
  const float* Hin = x;
  size_t soff = 0, coff = 0;

  for (int i = 0; i < 4; ++i) {
    int C = Cin[i], oc = Cout[i];
    int l2 = (oc == 64) ? 6 : (oc == 128) ? 7 : 8;
    double* sum = stats + soff;  double* sumsq = sum + oc;  soff += 2 * (size_t)oc;
    float* cA = coefb + coff;    float* cC = cA + oc;       coff += 2 * (size_t)oc;

    xx_kernel<<<32, 256, 0, stream>>>(Hin, C, xxb);
    dist_kernel<<<dim3(16, 16, 8), 256, 0, stream>>>(Hin, C, xxb, DD);
    topk_kernel<<<2048, 256, 0, stream>>>(DD, idxb);
    wcat_kernel<<<(oc * C + 255) / 256, 256, 0, stream>>>(W[i], wcat, oc, C);
    pt_gemm<<<dim3(2 * oc / 64, 128), 256, 0, stream>>>(Hin, wcat, PT, C, 2 * oc);
    edge_reduce<<<512, 256, 0, stream>>>(PT, idxb, ymax, ymin, sum, sumsq, oc, l2);
    coef_kernel<<<1, 256, 0, stream>>>(sum, sumsq, g[i], bb[i], cA, cC, oc, 163840.0);
    edge_epi<<<(8192 * oc) / 256, 256, 0, stream>>>(ymax, ymin, cA, cC, Hbuf, fusedb, oc, l2, choff[i]);
    Hin = Hbuf;
  }

  double* sumF = stats + soff;  double* sumsqF = sumF + 1024;
  float* cAF = coefb + coff;    float* cCF = cAF + 1024;
  final_gemm_mfma<<<dim3(8, 64), 256, 0, stream>>>(fusedb, wfb, yf);
  col_stats<<<dim3(4, 64), 256, 0, stream>>>(yf, sumF, sumsqF);
  coef_kernel<<<4, 256, 0, stream>>>(sumF, sumsqF, gf, bfp, cAF, cCF, 1024, 8192.0);
  final_epi<<<8192 * 1024 / 256, 256, 0, stream>>>(yf, cAF, cCF, out);
}